// Round 16
// baseline (86.172 us; speedup 1.0000x reference)
//
#include <hip/hip_runtime.h>
#include <math.h>

#define N_FILT 64
#define IMG_DIM 256
#define IMG_SZ (256*256)
#define HDIM 1024
#define NBATCH 512

typedef __attribute__((ext_vector_type(4))) float f32x4;

// ws layout (131,328 B total):
//   int meta[64]: [0..15]=loY [16..31]=hiY     (16 n-groups of 4, stage 1)
//                 [32..47]=lo4X (granule-aligned) [48..63]=hiX (16 m-groups of 4)
//   byte 256           : fyg [16][256][4] float (gamma/SY folded, packed from lo,
//                        zero-filled beyond band)                      64 KiB
//   byte 256+65536     : fxg [16][256][4] float (1/SX folded, packed from lo4,
//                        zero-filled)                                   64 KiB

// grid = 2 x 1024 threads: block 0 builds the Y side (fyg), block 1 the X side.
__global__ __launch_bounds__(1024) void k_prep(
    const float* __restrict__ h, const float* __restrict__ Ww,
    const float* __restrict__ Wb, int* __restrict__ meta,
    float* __restrict__ fyg, float* __restrict__ fxg)
{
  __shared__ float partial[16*8];    // [wave][slot]
  __shared__ float par_s[8];
  __shared__ float F[N_FILT*IMG_DIM];        // 64 KiB
  __shared__ int s_lo[64], s_hi[64], s_glo[16], s_ghi[16];
  __shared__ float ssum[16];
  const int t   = threadIdx.x;               // 0..1023
  const int side= blockIdx.x;                // 0=Y, 1=X
  const int wv  = t>>6, ln = t&63;
  float* __restrict__ wout = side ? fxg : fyg;

  // zero-fill this side's weight buffer (packs only overwrite in-band rows)
  {
    float4 z = make_float4(0.f,0.f,0.f,0.f);
    float4* p = (float4*)wout;
    #pragma unroll
    for (int k=0;k<4;++k) p[t + 1024*k] = z;
  }

  // ---- params[j] = h[0] . W_read_w[j] + W_read_b[j] (1 elem per thread) ----
  {
    const float hv = h[t];                   // HDIM == 1024 == blockDim.x
    float s0 = hv*Ww[t];
    float s1 = hv*Ww[HDIM+t];
    float s2 = hv*Ww[2*HDIM+t];
    float s3 = hv*Ww[3*HDIM+t];
    float s4 = hv*Ww[4*HDIM+t];
    #pragma unroll
    for (int o=32;o>0;o>>=1){
      s0+=__shfl_down(s0,o); s1+=__shfl_down(s1,o); s2+=__shfl_down(s2,o);
      s3+=__shfl_down(s3,o); s4+=__shfl_down(s4,o);
    }
    if (ln==0){ partial[wv*8+0]=s0; partial[wv*8+1]=s1; partial[wv*8+2]=s2;
                partial[wv*8+3]=s3; partial[wv*8+4]=s4; }
  }
  __syncthreads();
  if (t<5){
    float s = Wb[t];
    #pragma unroll
    for (int k=0;k<16;++k) s += partial[k*8+t];
    par_s[t] = s;
  }
  __syncthreads();

  const float var   = expf(par_s[2]+1e-8f);
  const float dt    = expf(par_s[3]);
  const float gamma = expf(par_s[4]);
  const float gC = 0.5f*257.f*(par_s[side?0:1]+1.f);  // Y<-par[1], X<-par[0]
  const float d  = dt*(255.f/63.f);
  const float sub= -32.5f*d;
  const float inv2v = 1.f/(2.f*var);
  const float w88v  = 88.f*var;   // band cutoff: e(a)/e(peak) >= exp(-44)

  if (t<64){
    float mu = gC + sub + d*(float)t;
    float astar = fminf(255.f, fmaxf(0.f, rintf(mu)));   // clamped peak
    float t0 = (astar-mu)*(astar-mu);
    float r  = sqrtf(t0 + w88v);
    int lo = (int)ceilf(mu-r); int hi = (int)floorf(mu+r)+1;
    lo = lo<0?0:lo; hi = hi>256?256:hi; if (hi<lo) hi=lo;
    s_lo[t]=lo; s_hi[t]=hi;
  }
  __syncthreads();
  if (t<16){
    int lo=256, hi=0;
    #pragma unroll
    for (int k2=0;k2<4;++k2){ lo=min(lo,s_lo[t*4+k2]); hi=max(hi,s_hi[t*4+k2]); }
    if (hi<lo){lo=0;hi=0;}
    if (side==0){ meta[t]=lo; meta[16+t]=hi; }
    else        { lo &= ~3;  meta[32+t]=lo; meta[48+t]=hi; }  // granule-aligned
    s_glo[t]=lo; s_ghi[t]=hi;
  }
  // F + global sum (16 elems per thread)
  float sum=0.f;
  #pragma unroll
  for (int k=0;k<16;++k){
    int idx=t+1024*k;
    int n=idx>>8, a=idx&255;
    float mu = gC+sub+d*(float)n;
    float dx=(float)a-mu;
    float e=expf(-dx*dx*inv2v);
    F[idx]=e; sum+=e;
  }
  #pragma unroll
  for (int o=32;o>0;o>>=1) sum+=__shfl_down(sum,o);
  if (ln==0) ssum[wv]=sum;
  __syncthreads();
  float stot = 0.f;
  #pragma unroll
  for (int k=0;k<16;++k) stot += ssum[k];    // uniform across threads
  const float sc = (side==0 ? gamma : 1.f)/stot;   // fold gamma into Y side
  #pragma unroll
  for (int k=0;k<16;++k){
    int idx=t+1024*k;
    int n=idx>>8, a=idx&255, g=n>>2;
    int lo=s_glo[g], hi=s_ghi[g];
    if (a>=lo && a<hi) wout[(size_t)((g<<10)+((a-lo)<<2)+(n&3))] = F[idx]*sc;
  }
}

// 2048 blocks: each owns an (x, x_hat) IMAGE PAIR p and quad qq (16 filters).
// 4 waves; wave w owns stage-1 n-group g=qq*4+w (both images) and stage-2
// m-group q=w*4+(lane>>4) (both images).
// Stage 1: PLAIN per-lane float4 loads (two independent streams A/B per
// iteration -> natural 2-deep MLP), exact band bounds (no junk fetch),
// relative-packed zero-filled weights (uniform s_load). No asm, no ring:
// LDS = 32 KiB -> 5 blocks/CU (20 waves) — occupancy is the one variable
// that measurably moved BW across rounds 1-15.
__global__ __launch_bounds__(256, 5) void k_main(
    const float* __restrict__ x, const float* __restrict__ xh,
    const int* __restrict__ meta, const float* __restrict__ fyg,
    const float* __restrict__ fxg, float* __restrict__ out)
{
  __shared__ float POOL[8192];   // 32 KiB: TT_A [0..4095], TT_B [4096..8191]
  // transpose bufs overlay TT_A after a barrier: TRA = POOL[0..], TRB = POOL[1280..]
  const int bid = blockIdx.x;
  const int lg  = ((bid&7)<<8) | (bid>>3);   // 2048 blocks, bijective
  const int p   = lg>>2, qq = lg&3;
  const int tid = threadIdx.x;
  const int w    = __builtin_amdgcn_readfirstlane(tid>>6);
  const int lane = tid & 63;
  const float* __restrict__ srcA = x  + (size_t)p*IMG_SZ;
  const float* __restrict__ srcB = xh + (size_t)p*IMG_SZ;
  float* __restrict__ dstA = out + (size_t)p*8192 + qq*1024;
  float* __restrict__ dstB = dstA + 4096;

  float accA[4][4], accB[4][4];
  // ---- stage 1: T[n][b] = sum_a FY[n][a]*src[a][b] for BOTH images ----
  {
    const int g  = qq*4 + w;
    const int a0 = __builtin_amdgcn_readfirstlane(meta[g]);
    const int a1 = __builtin_amdgcn_readfirstlane(meta[16+g]);
    const int R  = a1 - a0;                    // rows in band (may be 0)
    const float* const wp = fyg + ((size_t)g<<10);   // [256][4] rel., zero-padded
    const float* const sA = srcA + ((size_t)a0<<8) + (lane<<2);
    const float* const sB = srcB + ((size_t)a0<<8) + (lane<<2);
    #pragma unroll
    for (int k2=0;k2<4;++k2){
      accA[k2][0]=0.f;accA[k2][1]=0.f;accA[k2][2]=0.f;accA[k2][3]=0.f;
      accB[k2][0]=0.f;accB[k2][1]=0.f;accB[k2][2]=0.f;accB[k2][3]=0.f;
    }

#define FMAROW(ACC,W,T) do{ \
    ACC[0][0]=fmaf(W.x,T.x,ACC[0][0]); ACC[0][1]=fmaf(W.x,T.y,ACC[0][1]); \
    ACC[0][2]=fmaf(W.x,T.z,ACC[0][2]); ACC[0][3]=fmaf(W.x,T.w,ACC[0][3]); \
    ACC[1][0]=fmaf(W.y,T.x,ACC[1][0]); ACC[1][1]=fmaf(W.y,T.y,ACC[1][1]); \
    ACC[1][2]=fmaf(W.y,T.z,ACC[1][2]); ACC[1][3]=fmaf(W.y,T.w,ACC[1][3]); \
    ACC[2][0]=fmaf(W.z,T.x,ACC[2][0]); ACC[2][1]=fmaf(W.z,T.y,ACC[2][1]); \
    ACC[2][2]=fmaf(W.z,T.z,ACC[2][2]); ACC[2][3]=fmaf(W.z,T.w,ACC[2][3]); \
    ACC[3][0]=fmaf(W.w,T.x,ACC[3][0]); ACC[3][1]=fmaf(W.w,T.y,ACC[3][1]); \
    ACC[3][2]=fmaf(W.w,T.z,ACC[3][2]); ACC[3][3]=fmaf(W.w,T.w,ACC[3][3]); }while(0)

    #pragma unroll 2
    for (int r=0; r<R; ++r){
      const float4 tA = *(const float4* __restrict__)(sA + (r<<8));
      const float4 tB = *(const float4* __restrict__)(sB + (r<<8));
      const f32x4 wv = ((const f32x4*)wp)[r];   // wave-uniform -> s_load
      FMAROW(accA, wv, tA);
      FMAROW(accB, wv, tB);
    }
  }
  __syncthreads();   // (uniform) order stage-1 epoch before TT writes
  // b128 writes into TT_A / TT_B, granule-XOR swizzle (lane ^ n)
  #pragma unroll
  for (int k2=0;k2<4;++k2){
    const int n = w*4 + k2;                    // wave-uniform row (0..15)
    float4 va; va.x=accA[k2][0]; va.y=accA[k2][1]; va.z=accA[k2][2]; va.w=accA[k2][3];
    float4 vb; vb.x=accB[k2][0]; vb.y=accB[k2][1]; vb.z=accB[k2][2]; vb.w=accB[k2][3];
    *(float4*)&POOL[       (n<<8) + ((lane ^ n)<<2)] = va;
    *(float4*)&POOL[4096 + (n<<8) + ((lane ^ n)<<2)] = vb;
  }
  __syncthreads();

  // ---- stage 2: out[n][m] = sum_b T[n][b]*FX[m][b]; lane = cc*16 + nl ----
  const int nl = lane & 15;
  const int cc = lane >> 4;
  const int q  = w*4 + cc;                     // one m-group of 4 per (wave,cc)
  const int lo4 = meta[32+q];
  const int hi  = meta[48+q];
  int ngu = (hi - lo4 + 3) >> 2;
  ngu = max(ngu, __shfl_xor(ngu,16));          // wave-uniform trip count
  ngu = max(ngu, __shfl_xor(ngu,32));          // (overrun iters: zero weights)
  const int u0  = lo4 >> 2;
  const float* wq = fxg + ((size_t)q<<10);     // [256][4] rows packed from lo4
  float oA0=0.f,oA1=0.f,oA2=0.f,oA3=0.f;
  float oB0=0.f,oB1=0.f,oB2=0.f,oB3=0.f;
  #pragma unroll 2
  for (int it=0; it<ngu; it+=2){
    const int uA_ = min(u0+it,   63);
    const int uB_ = min(u0+it+1, 63);
    const float4 tA0 = *(const float4*)&POOL[       (nl<<8) + ((uA_^nl)<<2)];
    const float4 tA1 = *(const float4*)&POOL[       (nl<<8) + ((uB_^nl)<<2)];
    const float4 tB0 = *(const float4*)&POOL[4096 + (nl<<8) + ((uA_^nl)<<2)];
    const float4 tB1 = *(const float4*)&POOL[4096 + (nl<<8) + ((uB_^nl)<<2)];
    const float4 a0w = *(const float4*)(wq + it*16);      // shared by A and B
    const float4 a1w = *(const float4*)(wq + it*16 + 4);
    const float4 a2w = *(const float4*)(wq + it*16 + 8);
    const float4 a3w = *(const float4*)(wq + it*16 + 12);
    const float4 b0w = *(const float4*)(wq + it*16 + 16);
    const float4 b1w = *(const float4*)(wq + it*16 + 20);
    const float4 b2w = *(const float4*)(wq + it*16 + 24);
    const float4 b3w = *(const float4*)(wq + it*16 + 28);
    oA0=fmaf(tA0.x,a0w.x,fmaf(tA0.y,a1w.x,fmaf(tA0.z,a2w.x,fmaf(tA0.w,a3w.x,oA0))));
    oA1=fmaf(tA0.x,a0w.y,fmaf(tA0.y,a1w.y,fmaf(tA0.z,a2w.y,fmaf(tA0.w,a3w.y,oA1))));
    oA2=fmaf(tA0.x,a0w.z,fmaf(tA0.y,a1w.z,fmaf(tA0.z,a2w.z,fmaf(tA0.w,a3w.z,oA2))));
    oA3=fmaf(tA0.x,a0w.w,fmaf(tA0.y,a1w.w,fmaf(tA0.z,a2w.w,fmaf(tA0.w,a3w.w,oA3))));
    oB0=fmaf(tB0.x,a0w.x,fmaf(tB0.y,a1w.x,fmaf(tB0.z,a2w.x,fmaf(tB0.w,a3w.x,oB0))));
    oB1=fmaf(tB0.x,a0w.y,fmaf(tB0.y,a1w.y,fmaf(tB0.z,a2w.y,fmaf(tB0.w,a3w.y,oB1))));
    oB2=fmaf(tB0.x,a0w.z,fmaf(tB0.y,a1w.z,fmaf(tB0.z,a2w.z,fmaf(tB0.w,a3w.z,oB2))));
    oB3=fmaf(tB0.x,a0w.w,fmaf(tB0.y,a1w.w,fmaf(tB0.z,a2w.w,fmaf(tB0.w,a3w.w,oB3))));
    if (it+1 < ngu){
      oA0=fmaf(tA1.x,b0w.x,fmaf(tA1.y,b1w.x,fmaf(tA1.z,b2w.x,fmaf(tA1.w,b3w.x,oA0))));
      oA1=fmaf(tA1.x,b0w.y,fmaf(tA1.y,b1w.y,fmaf(tA1.z,b2w.y,fmaf(tA1.w,b3w.y,oA1))));
      oA2=fmaf(tA1.x,b0w.z,fmaf(tA1.y,b1w.z,fmaf(tA1.z,b2w.z,fmaf(tA1.w,b3w.z,oA2))));
      oA3=fmaf(tA1.x,b0w.w,fmaf(tA1.y,b1w.w,fmaf(tA1.z,b2w.w,fmaf(tA1.w,b3w.w,oA3))));
      oB0=fmaf(tB1.x,b0w.x,fmaf(tB1.y,b1w.x,fmaf(tB1.z,b2w.x,fmaf(tB1.w,b3w.x,oB0))));
      oB1=fmaf(tB1.x,b0w.y,fmaf(tB1.y,b1w.y,fmaf(tB1.z,b2w.y,fmaf(tB1.w,b3w.y,oB1))));
      oB2=fmaf(tB1.x,b0w.z,fmaf(tB1.y,b1w.z,fmaf(tB1.z,b2w.z,fmaf(tB1.w,b3w.z,oB2))));
      oB3=fmaf(tB1.x,b0w.w,fmaf(tB1.y,b1w.w,fmaf(tB1.z,b2w.w,fmaf(tB1.w,b3w.w,oB3))));
    }
  }
  __syncthreads();   // all stage-2 TT reads done before transpose overlay
  // transpose bufs overlay TT_A: TRA = POOL[0..1087], TRB = POOL[1280..2367]
  {
    const int m0 = q*4;
    POOL[       nl*68 + m0 + 0] = oA0; POOL[       nl*68 + m0 + 1] = oA1;
    POOL[       nl*68 + m0 + 2] = oA2; POOL[       nl*68 + m0 + 3] = oA3;
    POOL[1280 + nl*68 + m0 + 0] = oB0; POOL[1280 + nl*68 + m0 + 1] = oB1;
    POOL[1280 + nl*68 + m0 + 2] = oB2; POOL[1280 + nl*68 + m0 + 3] = oB3;
  }
  __syncthreads();
  {
    const int f = tid*4;
    const int n = f>>6, m = f&63;
    *(float4*)(dstA+f) = *(const float4*)&POOL[       n*68 + m];
    *(float4*)(dstB+f) = *(const float4*)&POOL[1280 + n*68 + m];
  }
#undef FMAROW
}

extern "C" void kernel_launch(void* const* d_in, const int* in_sizes, int n_in,
                              void* d_out, int out_size, void* d_ws, size_t ws_size,
                              hipStream_t stream)
{
  const float* x  = (const float*)d_in[0];
  const float* xh = (const float*)d_in[1];
  const float* h  = (const float*)d_in[2];   // only row 0 is used
  const float* Ww = (const float*)d_in[3];
  const float* Wb = (const float*)d_in[4];
  float* out = (float*)d_out;

  int*   meta = (int*)d_ws;
  float* fyg  = (float*)((char*)d_ws + 256);
  float* fxg  = (float*)((char*)d_ws + 256 + 65536);

  k_prep<<<2, 1024, 0, stream>>>(h, Ww, Wb, meta, fyg, fxg);
  k_main<<<4*NBATCH, 256, 0, stream>>>(x, xh, meta, fyg, fxg, out);
}

// Round 17
// 85.046 us; speedup vs baseline: 1.0132x; 1.0132x over previous
//
#include <hip/hip_runtime.h>
#include <math.h>

#define N_FILT 64
#define IMG_DIM 256
#define IMG_SZ (256*256)
#define HDIM 1024
#define NBATCH 512

typedef __attribute__((ext_vector_type(4))) float f32x4;
typedef __attribute__((address_space(3))) float lds_float;

// ws layout (131,328 B total):
//   int meta[64]: [0..15]=loY [16..31]=hiY     (16 n-groups of 4, stage 1)
//                 [32..47]=lo4X (granule-aligned) [48..63]=hiX (16 m-groups of 4)
//   byte 256           : fyg [16][256][4] float (gamma/SY folded, packed from lo,
//                        zero-filled beyond band)                      64 KiB
//   byte 256+65536     : fxg [16][256][4] float (1/SX folded, packed from lo4,
//                        zero-filled)                                   64 KiB

// async DMA: one wave-issue copies 64 lanes x 16B = 1KB row into LDS at
// wave-uniform base + lane*16 (gfx950 global_load_lds_dwordx4).
__device__ __forceinline__ void gl_lds16(const float* g, float* l){
  __builtin_amdgcn_global_load_lds(
      (const __attribute__((address_space(1))) unsigned int*)g,
      (__attribute__((address_space(3))) unsigned int*)l,
      16, 0, 0);
}

// grid = 2 x 1024 threads: block 0 builds the Y side (fyg), block 1 the X side
// (fxg). Widened from 256 to 1024 threads to shrink the serial prefix ~4x.
__global__ __launch_bounds__(1024) void k_prep(
    const float* __restrict__ h, const float* __restrict__ Ww,
    const float* __restrict__ Wb, int* __restrict__ meta,
    float* __restrict__ fyg, float* __restrict__ fxg)
{
  __shared__ float partial[16*8];    // [wave][slot]
  __shared__ float par_s[8];
  __shared__ float F[N_FILT*IMG_DIM];        // 64 KiB
  __shared__ int s_lo[64], s_hi[64], s_glo[16], s_ghi[16];
  __shared__ float ssum[16];
  const int t   = threadIdx.x;               // 0..1023
  const int side= blockIdx.x;                // 0=Y, 1=X
  const int wv  = t>>6, ln = t&63;
  float* __restrict__ wout = side ? fxg : fyg;

  // zero-fill this side's weight buffer (packs only overwrite in-band rows)
  {
    float4 z = make_float4(0.f,0.f,0.f,0.f);
    float4* p = (float4*)wout;
    #pragma unroll
    for (int k=0;k<4;++k) p[t + 1024*k] = z;
  }

  // ---- params[j] = h[0] . W_read_w[j] + W_read_b[j] (1 elem per thread) ----
  {
    const float hv = h[t];                   // HDIM == 1024 == blockDim.x
    float s0 = hv*Ww[t];
    float s1 = hv*Ww[HDIM+t];
    float s2 = hv*Ww[2*HDIM+t];
    float s3 = hv*Ww[3*HDIM+t];
    float s4 = hv*Ww[4*HDIM+t];
    #pragma unroll
    for (int o=32;o>0;o>>=1){
      s0+=__shfl_down(s0,o); s1+=__shfl_down(s1,o); s2+=__shfl_down(s2,o);
      s3+=__shfl_down(s3,o); s4+=__shfl_down(s4,o);
    }
    if (ln==0){ partial[wv*8+0]=s0; partial[wv*8+1]=s1; partial[wv*8+2]=s2;
                partial[wv*8+3]=s3; partial[wv*8+4]=s4; }
  }
  __syncthreads();
  if (t<5){
    float s = Wb[t];
    #pragma unroll
    for (int k=0;k<16;++k) s += partial[k*8+t];
    par_s[t] = s;
  }
  __syncthreads();

  const float var   = expf(par_s[2]+1e-8f);
  const float dt    = expf(par_s[3]);
  const float gamma = expf(par_s[4]);
  const float gC = 0.5f*257.f*(par_s[side?0:1]+1.f);  // Y<-par[1], X<-par[0]
  const float d  = dt*(255.f/63.f);
  const float sub= -32.5f*d;
  const float inv2v = 1.f/(2.f*var);
  const float w88v  = 88.f*var;   // band cutoff: e(a)/e(peak) >= exp(-44)

  if (t<64){
    float mu = gC + sub + d*(float)t;
    float astar = fminf(255.f, fmaxf(0.f, rintf(mu)));   // clamped peak
    float t0 = (astar-mu)*(astar-mu);
    float r  = sqrtf(t0 + w88v);
    int lo = (int)ceilf(mu-r); int hi = (int)floorf(mu+r)+1;
    lo = lo<0?0:lo; hi = hi>256?256:hi; if (hi<lo) hi=lo;
    s_lo[t]=lo; s_hi[t]=hi;
  }
  __syncthreads();
  if (t<16){
    int lo=256, hi=0;
    #pragma unroll
    for (int k2=0;k2<4;++k2){ lo=min(lo,s_lo[t*4+k2]); hi=max(hi,s_hi[t*4+k2]); }
    if (hi<lo){lo=0;hi=0;}
    if (side==0){ meta[t]=lo; meta[16+t]=hi; }
    else        { lo &= ~3;  meta[32+t]=lo; meta[48+t]=hi; }  // granule-aligned
    s_glo[t]=lo; s_ghi[t]=hi;
  }
  // F + global sum (16 elems per thread)
  float sum=0.f;
  #pragma unroll
  for (int k=0;k<16;++k){
    int idx=t+1024*k;
    int n=idx>>8, a=idx&255;
    float mu = gC+sub+d*(float)n;
    float dx=(float)a-mu;
    float e=expf(-dx*dx*inv2v);
    F[idx]=e; sum+=e;
  }
  #pragma unroll
  for (int o=32;o>0;o>>=1) sum+=__shfl_down(sum,o);
  if (ln==0) ssum[wv]=sum;
  __syncthreads();
  float stot = 0.f;
  #pragma unroll
  for (int k=0;k<16;++k) stot += ssum[k];    // uniform across threads
  const float sc = (side==0 ? gamma : 1.f)/stot;   // fold gamma into Y side
  #pragma unroll
  for (int k=0;k<16;++k){
    int idx=t+1024*k;
    int n=idx>>8, a=idx&255, g=n>>2;
    int lo=s_glo[g], hi=s_ghi[g];
    if (a>=lo && a<hi) wout[(size_t)((g<<10)+((a-lo)<<2)+(n&3))] = F[idx]*sc;
  }
}

// 2048 blocks: each owns an (x, x_hat) IMAGE PAIR p and quad qq (16 filters).
// 4 waves; wave w owns stage-1 n-group g=qq*4+w (both images) and stage-2
// m-group q=w*4+(lane>>4) (both images).
// Stage 1 = round-8 ring machinery doubled: 4 chunk-slots x (2 rows x 2 imgs),
// depth-3-chunk lookahead (12 DMAs / 12 KB per wave in flight), constant
// clobber-free s_waitcnt vmcnt(12), asm ds_read consume (rule-18 recipe).
// Halves block generations (16->8 per CU) and amortizes all fixed costs x2.
__global__ __launch_bounds__(256, 2) void k_main(
    const float* __restrict__ x, const float* __restrict__ xh,
    const int* __restrict__ meta, const float* __restrict__ fyg,
    const float* __restrict__ fxg, float* __restrict__ out)
{
  __shared__ float POOL[16384];   // 64 KiB
  // stage1 ring: POOL[w*4096 + slot*1024 + {0:A0, 256:B0, 512:A1, 768:B1}]
  // overlay:     TT_A = POOL[0..4095], TT_B = POOL[4096..8191]
  //              TRA  = POOL[8192..9279], TRB = POOL[9472..10559]
  const int bid = blockIdx.x;
  const int lg  = ((bid&7)<<8) | (bid>>3);   // 2048 blocks, bijective
  const int p   = lg>>2, qq = lg&3;
  const int tid = threadIdx.x;
  const int w    = __builtin_amdgcn_readfirstlane(tid>>6);
  const int lane = tid & 63;
  const float* __restrict__ srcA = x  + (size_t)p*IMG_SZ;
  const float* __restrict__ srcB = xh + (size_t)p*IMG_SZ;
  float* __restrict__ dstA = out + (size_t)p*8192 + qq*1024;
  float* __restrict__ dstB = dstA + 4096;

  float accA[4][4], accB[4][4];
  // ---- stage 1: T[n][b] = sum_a FY[n][a]*src[a][b] for BOTH images ----
  {
    const int g  = qq*4 + w;
    const int a0 = __builtin_amdgcn_readfirstlane(meta[g]);
    const int a1 = __builtin_amdgcn_readfirstlane(meta[16+g]);
    const int R  = a1 - a0;                    // rows in band (may be 0)
    const int CC = (R + 1) >> 1;               // 2-row chunks
    const float* const wp = fyg + ((size_t)g<<10);   // [256][4] rel., zero-padded
    const float* const sA = srcA + (lane<<2);
    const float* const sB = srcB + (lane<<2);
    #pragma unroll
    for (int k2=0;k2<4;++k2){
      accA[k2][0]=0.f;accA[k2][1]=0.f;accA[k2][2]=0.f;accA[k2][3]=0.f;
      accB[k2][0]=0.f;accB[k2][1]=0.f;accB[k2][2]=0.f;accB[k2][3]=0.f;
    }

#define DMA4(ch) do{ const int _c=(ch); const int _r0=a0+2*_c; \
    float* const _b = &POOL[(w<<12) + ((_c&3)<<10)]; \
    gl_lds16(sA + ((size_t)min(_r0,  255)<<8), _b); \
    gl_lds16(sB + ((size_t)min(_r0,  255)<<8), _b+256); \
    gl_lds16(sA + ((size_t)min(_r0+1,255)<<8), _b+512); \
    gl_lds16(sB + ((size_t)min(_r0+1,255)<<8), _b+768); }while(0)
#define FMAROW(ACC,W,T) do{ \
    ACC[0][0]=fmaf(W.x,T.x,ACC[0][0]); ACC[0][1]=fmaf(W.x,T.y,ACC[0][1]); \
    ACC[0][2]=fmaf(W.x,T.z,ACC[0][2]); ACC[0][3]=fmaf(W.x,T.w,ACC[0][3]); \
    ACC[1][0]=fmaf(W.y,T.x,ACC[1][0]); ACC[1][1]=fmaf(W.y,T.y,ACC[1][1]); \
    ACC[1][2]=fmaf(W.y,T.z,ACC[1][2]); ACC[1][3]=fmaf(W.y,T.w,ACC[1][3]); \
    ACC[2][0]=fmaf(W.z,T.x,ACC[2][0]); ACC[2][1]=fmaf(W.z,T.y,ACC[2][1]); \
    ACC[2][2]=fmaf(W.z,T.z,ACC[2][2]); ACC[2][3]=fmaf(W.z,T.w,ACC[2][3]); \
    ACC[3][0]=fmaf(W.w,T.x,ACC[3][0]); ACC[3][1]=fmaf(W.w,T.y,ACC[3][1]); \
    ACC[3][2]=fmaf(W.w,T.z,ACC[3][2]); ACC[3][3]=fmaf(W.w,T.w,ACC[3][3]); }while(0)

    if (R > 0){
      // ring prologue: 3 chunks (12 DMAs, 12 KB) in flight
      DMA4(0); DMA4(1); DMA4(2);
      #pragma unroll 1
      for (int c=0; c<CC; ++c){
        DMA4(c+3);                             // 16 outstanding after issue
        __builtin_amdgcn_sched_barrier(0);
        asm volatile("s_waitcnt vmcnt(12)");   // chunk c landed; 3 in flight
        __builtin_amdgcn_sched_barrier(0);
        f32x4 tA0,tB0,tA1,tB1;
        lds_float* l0 = (lds_float*)&POOL[(w<<12) + ((c&3)<<10) + (lane<<2)];
        asm volatile("ds_read_b128 %0, %1"             : "=&v"(tA0) : "v"(l0));
        asm volatile("ds_read_b128 %0, %1 offset:1024" : "=&v"(tB0) : "v"(l0));
        asm volatile("ds_read_b128 %0, %1 offset:2048" : "=&v"(tA1) : "v"(l0));
        asm volatile("ds_read_b128 %0, %1 offset:3072" : "=&v"(tB1) : "v"(l0));
        // relative rows: 2c <= 255; 2c+1 <= R <= 256 -> clamp; zero-fill beyond band
        const f32x4 w0 = ((const f32x4*)wp)[min(2*c,  255)];   // uniform s_load
        const f32x4 w1 = ((const f32x4*)wp)[min(2*c+1,255)];
        asm volatile("s_waitcnt lgkmcnt(0)");
        __builtin_amdgcn_sched_barrier(0);
        FMAROW(accA,w0,tA0); FMAROW(accB,w0,tB0);
        FMAROW(accA,w1,tA1); FMAROW(accB,w1,tB1);
      }
      asm volatile("s_waitcnt vmcnt(0)");      // per-wave drain before overlay
    }
#undef DMA4
  }
  __syncthreads();                             // all waves' DMAs retired
  // b128 writes into TT_A / TT_B, granule-XOR swizzle (lane ^ n)
  #pragma unroll
  for (int k2=0;k2<4;++k2){
    const int n = w*4 + k2;                    // wave-uniform row (0..15)
    float4 va; va.x=accA[k2][0]; va.y=accA[k2][1]; va.z=accA[k2][2]; va.w=accA[k2][3];
    float4 vb; vb.x=accB[k2][0]; vb.y=accB[k2][1]; vb.z=accB[k2][2]; vb.w=accB[k2][3];
    *(float4*)&POOL[       (n<<8) + ((lane ^ n)<<2)] = va;
    *(float4*)&POOL[4096 + (n<<8) + ((lane ^ n)<<2)] = vb;
  }
  __syncthreads();

  // ---- stage 2: out[n][m] = sum_b T[n][b]*FX[m][b]; lane = cc*16 + nl ----
  const int nl = lane & 15;
  const int cc = lane >> 4;
  const int q  = w*4 + cc;                     // one m-group of 4 per (wave,cc)
  const int lo4 = meta[32+q];
  const int hi  = meta[48+q];
  int ngu = (hi - lo4 + 3) >> 2;
  ngu = max(ngu, __shfl_xor(ngu,16));          // wave-uniform trip count
  ngu = max(ngu, __shfl_xor(ngu,32));          // (overrun iters: zero weights)
  const int u0  = lo4 >> 2;
  const float* wq = fxg + ((size_t)q<<10);     // [256][4] rows packed from lo4
  float oA0=0.f,oA1=0.f,oA2=0.f,oA3=0.f;
  float oB0=0.f,oB1=0.f,oB2=0.f,oB3=0.f;
  #pragma unroll 2
  for (int it=0; it<ngu; it+=2){
    const int uA_ = min(u0+it,   63);
    const int uB_ = min(u0+it+1, 63);
    const float4 tA0 = *(const float4*)&POOL[       (nl<<8) + ((uA_^nl)<<2)];
    const float4 tA1 = *(const float4*)&POOL[       (nl<<8) + ((uB_^nl)<<2)];
    const float4 tB0 = *(const float4*)&POOL[4096 + (nl<<8) + ((uA_^nl)<<2)];
    const float4 tB1 = *(const float4*)&POOL[4096 + (nl<<8) + ((uB_^nl)<<2)];
    const float4 a0w = *(const float4*)(wq + it*16);      // shared by A and B
    const float4 a1w = *(const float4*)(wq + it*16 + 4);
    const float4 a2w = *(const float4*)(wq + it*16 + 8);
    const float4 a3w = *(const float4*)(wq + it*16 + 12);
    const float4 b0w = *(const float4*)(wq + it*16 + 16);
    const float4 b1w = *(const float4*)(wq + it*16 + 20);
    const float4 b2w = *(const float4*)(wq + it*16 + 24);
    const float4 b3w = *(const float4*)(wq + it*16 + 28);
    oA0=fmaf(tA0.x,a0w.x,fmaf(tA0.y,a1w.x,fmaf(tA0.z,a2w.x,fmaf(tA0.w,a3w.x,oA0))));
    oA1=fmaf(tA0.x,a0w.y,fmaf(tA0.y,a1w.y,fmaf(tA0.z,a2w.y,fmaf(tA0.w,a3w.y,oA1))));
    oA2=fmaf(tA0.x,a0w.z,fmaf(tA0.y,a1w.z,fmaf(tA0.z,a2w.z,fmaf(tA0.w,a3w.z,oA2))));
    oA3=fmaf(tA0.x,a0w.w,fmaf(tA0.y,a1w.w,fmaf(tA0.z,a2w.w,fmaf(tA0.w,a3w.w,oA3))));
    oB0=fmaf(tB0.x,a0w.x,fmaf(tB0.y,a1w.x,fmaf(tB0.z,a2w.x,fmaf(tB0.w,a3w.x,oB0))));
    oB1=fmaf(tB0.x,a0w.y,fmaf(tB0.y,a1w.y,fmaf(tB0.z,a2w.y,fmaf(tB0.w,a3w.y,oB1))));
    oB2=fmaf(tB0.x,a0w.z,fmaf(tB0.y,a1w.z,fmaf(tB0.z,a2w.z,fmaf(tB0.w,a3w.z,oB2))));
    oB3=fmaf(tB0.x,a0w.w,fmaf(tB0.y,a1w.w,fmaf(tB0.z,a2w.w,fmaf(tB0.w,a3w.w,oB3))));
    if (it+1 < ngu){
      oA0=fmaf(tA1.x,b0w.x,fmaf(tA1.y,b1w.x,fmaf(tA1.z,b2w.x,fmaf(tA1.w,b3w.x,oA0))));
      oA1=fmaf(tA1.x,b0w.y,fmaf(tA1.y,b1w.y,fmaf(tA1.z,b2w.y,fmaf(tA1.w,b3w.y,oA1))));
      oA2=fmaf(tA1.x,b0w.z,fmaf(tA1.y,b1w.z,fmaf(tA1.z,b2w.z,fmaf(tA1.w,b3w.z,oA2))));
      oA3=fmaf(tA1.x,b0w.w,fmaf(tA1.y,b1w.w,fmaf(tA1.z,b2w.w,fmaf(tA1.w,b3w.w,oA3))));
      oB0=fmaf(tB1.x,b0w.x,fmaf(tB1.y,b1w.x,fmaf(tB1.z,b2w.x,fmaf(tB1.w,b3w.x,oB0))));
      oB1=fmaf(tB1.x,b0w.y,fmaf(tB1.y,b1w.y,fmaf(tB1.z,b2w.y,fmaf(tB1.w,b3w.y,oB1))));
      oB2=fmaf(tB1.x,b0w.z,fmaf(tB1.y,b1w.z,fmaf(tB1.z,b2w.z,fmaf(tB1.w,b3w.z,oB2))));
      oB3=fmaf(tB1.x,b0w.w,fmaf(tB1.y,b1w.w,fmaf(tB1.z,b2w.w,fmaf(tB1.w,b3w.w,oB3))));
    }
  }
  // transpose bufs live at POOL[8192..] (dead ring space) — disjoint from TT,
  // so no barrier needed between stage-2 TT reads and these writes.
  {
    const int m0 = q*4;
    POOL[8192 + nl*68 + m0 + 0] = oA0; POOL[8192 + nl*68 + m0 + 1] = oA1;
    POOL[8192 + nl*68 + m0 + 2] = oA2; POOL[8192 + nl*68 + m0 + 3] = oA3;
    POOL[9472 + nl*68 + m0 + 0] = oB0; POOL[9472 + nl*68 + m0 + 1] = oB1;
    POOL[9472 + nl*68 + m0 + 2] = oB2; POOL[9472 + nl*68 + m0 + 3] = oB3;
  }
  __syncthreads();
  {
    const int f = tid*4;
    const int n = f>>6, m = f&63;
    *(float4*)(dstA+f) = *(const float4*)&POOL[8192 + n*68 + m];
    *(float4*)(dstB+f) = *(const float4*)&POOL[9472 + n*68 + m];
  }
#undef FMAROW
}

extern "C" void kernel_launch(void* const* d_in, const int* in_sizes, int n_in,
                              void* d_out, int out_size, void* d_ws, size_t ws_size,
                              hipStream_t stream)
{
  const float* x  = (const float*)d_in[0];
  const float* xh = (const float*)d_in[1];
  const float* h  = (const float*)d_in[2];   // only row 0 is used
  const float* Ww = (const float*)d_in[3];
  const float* Wb = (const float*)d_in[4];
  float* out = (float*)d_out;

  int*   meta = (int*)d_ws;
  float* fyg  = (float*)((char*)d_ws + 256);
  float* fxg  = (float*)((char*)d_ws + 256 + 65536);

  k_prep<<<2, 1024, 0, stream>>>(h, Ww, Wb, meta, fyg, fxg);
  k_main<<<4*NBATCH, 256, 0, stream>>>(x, xh, meta, fyg, fxg, out);
}